// Round 6
// baseline (305.899 us; speedup 1.0000x reference)
//
#include <hip/hip_runtime.h>

#define NTOK   8192     // B*T
#define DM     1024     // d_model
#define HD_    1024     // H*dh
#define TSEQ   4096
#define NCH    64       // TSEQ / 64
#define SROWS  72       // rows per state half ([d][i] 0-63, z row 64, pad 65-71)
#define SHALF  (SROWS*64)       // 4608 f16
#define SSTR   (2*SHALF)        // 9216 f16 per (bh,c)
#define ANG_STEP 3.8349519697141029e-4f   // pi / (2*4096)

typedef _Float16 h8_t  __attribute__((ext_vector_type(8)));
typedef _Float16 h4_t  __attribute__((ext_vector_type(4)));
typedef float    f32x4 __attribute__((ext_vector_type(4)));

__device__ __forceinline__ void gload16(const void* g, void* l) {
    __builtin_amdgcn_global_load_lds(
        (const __attribute__((address_space(1))) void*)g,
        (__attribute__((address_space(3))) void*)l, 16, 0, 0);
}

// ---------------------------------------------------------------------------
// f16 MFMA GEMM core. sm = 16 KB total: As [0,8K), Bs [8K,16K) during K-loop;
// epilogue staging Ct (16 KB) aliases the whole buffer after the post-loop
// barrier, flushed in TWO half-tile passes (keeps LDS at 16 KB).
// Epilogue modes: 0: f16 rows+relu (Q)  1: rows+relu + [bh][d][T] packs (K)
//                 2: packs only (V)     3: f32 rows (final out, no Ct)
// ---------------------------------------------------------------------------
__device__ __forceinline__ void gemm_core(
    const _Float16* __restrict__ A, const _Float16* __restrict__ Wt,
    const float* __restrict__ bias, int mode, int m_base, int n_base,
    _Float16* rows16, _Float16* tp16, float* rows32, char* sm)
{
    const int tid = threadIdx.x;
    const int lane = tid & 63, w = tid >> 6;

    const int r0 = tid >> 2;
    const int cb0 = (tid & 3) << 4;
    const _Float16* ga = A  + (size_t)(m_base + r0) * DM + (cb0 >> 1);
    const _Float16* gb = Wt + (size_t)(n_base + r0) * DM + (cb0 >> 1);
    char* lA = sm + w * 1024;
    char* lB = sm + 8192 + w * 1024;
    char* Ct = sm;                       // aliased epilogue staging (16 KB)

    f32x4 acc[4][4];
#pragma unroll
    for (int i = 0; i < 4; ++i)
#pragma unroll
        for (int j = 0; j < 4; ++j) acc[i][j] = (f32x4){0.f, 0.f, 0.f, 0.f};

    const int wm = (w >> 1) * 64, wn = (w & 1) * 64;
    const int fr = lane & 15;
    const int fk = (lane >> 4) * 16;

    for (int kt = 0; kt < DM / 32; ++kt) {
        const int k0 = kt * 32;
        __syncthreads();
        gload16(ga + k0,           lA);
        gload16(ga + 64 * DM + k0, lA + 4096);
        gload16(gb + k0,           lB);
        gload16(gb + 64 * DM + k0, lB + 4096);
        __syncthreads();
        h8_t a[4], b[4];
#pragma unroll
        for (int i = 0; i < 4; ++i) {
            a[i] = *(const h8_t*)(sm + (wm + i * 16 + fr) * 64 + fk);
            b[i] = *(const h8_t*)(sm + 8192 + (wn + i * 16 + fr) * 64 + fk);
        }
#pragma unroll
        for (int i = 0; i < 4; ++i)
#pragma unroll
            for (int j = 0; j < 4; ++j)
                acc[i][j] = __builtin_amdgcn_mfma_f32_16x16x32_f16(a[i], b[j], acc[i][j], 0, 0, 0);
    }

    // D layout (verified): col = lane&15 (+j*16), row = (lane>>4)*4 + reg (+i*16)
    const int rm = (lane >> 4) * 4;
    if (mode == 3) {
#pragma unroll
        for (int j = 0; j < 4; ++j) {
            const int col = n_base + wn + j * 16 + fr;
            const float bs = bias[col];
#pragma unroll
            for (int i = 0; i < 4; ++i) {
                const int m0 = m_base + wm + i * 16 + rm;
#pragma unroll
                for (int r = 0; r < 4; ++r)
                    rows32[(size_t)(m0 + r) * HD_ + col] = acc[i][j][r] + bs;
            }
        }
        return;
    }

    __syncthreads();   // all waves done with As/Bs -> Ct may alias them

    // ---- Phase R: row-major flush, 2 passes of 64 rows (modes 0,1; relu) ----
    if (mode <= 1) {
        const int myhalf = w >> 1;       // wm == myhalf*64
#pragma unroll
        for (int pass = 0; pass < 2; ++pass) {
            if (myhalf == pass) {
#pragma unroll
                for (int j = 0; j < 4; ++j) {
                    const int col = wn + j * 16 + fr;      // 0..127
                    const float bs = bias[n_base + col];
#pragma unroll
                    for (int i = 0; i < 4; ++i) {
#pragma unroll
                        for (int r = 0; r < 4; ++r) {
                            const int t = i * 16 + rm + r; // local row 0..63
                            const int byte = ((t << 8) + (col << 1)) ^ ((t & 15) << 4);
                            *(_Float16*)(Ct + byte) = (_Float16)fmaxf(acc[i][j][r] + bs, 0.f);
                        }
                    }
                }
            }
            __syncthreads();
#pragma unroll
            for (int p = 0; p < 4; ++p) {
                const int lin = p * 256 + tid;
                const int t = lin >> 4, d8 = lin & 15;
                h8_t v = *(const h8_t*)(Ct + (t << 8) + ((d8 ^ (t & 15)) << 4));
                *(h8_t*)(rows16 + (size_t)(m_base + pass * 64 + t) * HD_ + n_base + d8 * 8) = v;
            }
            __syncthreads();
        }
    }

    // ---- Phase T: [bh][d][T] transposed flush, 2 passes of 64 cols ----
    if (mode >= 1) {
        const int myside = w & 1;        // wn == myside*64
        const int bb = m_base >> 12;
        const int tl0 = m_base & 4095;
#pragma unroll
        for (int pass = 0; pass < 2; ++pass) {
            if (myside == pass) {
#pragma unroll
                for (int j = 0; j < 4; ++j) {
                    const int coll = j * 16 + fr;          // local col 0..63
                    const float bs = bias[n_base + pass * 64 + coll];
#pragma unroll
                    for (int i = 0; i < 4; ++i) {
                        const int ml0 = wm + i * 16 + rm;
                        h4_t pk;
#pragma unroll
                        for (int r = 0; r < 4; ++r) {
                            float v = acc[i][j][r] + bs;
                            if (mode == 1) v = fmaxf(v, 0.f);
                            pk[r] = (_Float16)v;
                        }
                        const int byte = ((coll << 8) + (ml0 << 1)) ^ ((coll & 15) << 4);
                        *(h4_t*)(Ct + byte) = pk;
                    }
                }
            }
            __syncthreads();
#pragma unroll
            for (int p = 0; p < 4; ++p) {
                const int lin = p * 256 + tid;
                const int d = lin >> 4, t8 = lin & 15;
                h8_t v = *(const h8_t*)(Ct + (d << 8) + ((t8 ^ (d & 15)) << 4));
                const int colg = n_base + pass * 64 + d;
                *(h8_t*)(tp16 + ((size_t)(bb * 16 + (colg >> 6)) * 64 + (colg & 63)) * TSEQ
                         + tl0 + t8 * 8) = v;
            }
            __syncthreads();
        }
    }
}

// z-innermost mapping: bx = mtile*3 + z, so 3 consecutive blocks share the
// same X panel (A-tile L2 reuse; X fetched once instead of 3x).
__global__ __launch_bounds__(256) void gemm_qkv(
    const _Float16* __restrict__ Xh, const _Float16* __restrict__ WtQKV,
    const float* __restrict__ bq, const float* __restrict__ bk, const float* __restrict__ bv,
    _Float16* __restrict__ Qh, _Float16* __restrict__ Kh,
    _Float16* __restrict__ KT, _Float16* __restrict__ VT)
{
    __shared__ char sm[16384];
    const int bx = blockIdx.x;
    const int z = bx % 3, mtile = bx / 3;
    const _Float16* Wt = WtQKV + (size_t)z * (DM * HD_);
    const float* bias = (z == 0) ? bq : (z == 1) ? bk : bv;
    _Float16* r16 = (z == 0) ? Qh : Kh;
    _Float16* t16 = (z == 1) ? KT : VT;
    gemm_core(Xh, Wt, bias, z, mtile * 128, blockIdx.y * 128, r16, t16, nullptr, sm);
}

__global__ __launch_bounds__(256) void gemm_out(
    const _Float16* __restrict__ A, const _Float16* __restrict__ Wt,
    const float* __restrict__ bias, float* __restrict__ out)
{
    __shared__ char sm[16384];
    gemm_core(A, Wt, bias, 3, blockIdx.x * 128, blockIdx.y * 128,
              nullptr, nullptr, out, sm);
}

// ---------------------------------------------------------------------------
// converts
// ---------------------------------------------------------------------------
__global__ __launch_bounds__(256) void conv_x_kernel(
    const float* __restrict__ x, _Float16* __restrict__ xh)
{
    const int i = blockIdx.x * 256 + threadIdx.x;
    float4 v = ((const float4*)x)[i];
    h4_t hv;
    hv[0] = (_Float16)v.x; hv[1] = (_Float16)v.y;
    hv[2] = (_Float16)v.z; hv[3] = (_Float16)v.w;
    ((h4_t*)xh)[i] = hv;
}

__global__ __launch_bounds__(256) void conv_wt4(
    const float* __restrict__ Wq, const float* __restrict__ Wk,
    const float* __restrict__ Wv, const float* __restrict__ Wo,
    _Float16* __restrict__ WtQKV, _Float16* __restrict__ WtO)
{
    __shared__ float t[32][33];
    const int z = blockIdx.z;
    const float* W = (z == 0) ? Wq : (z == 1) ? Wk : (z == 2) ? Wv : Wo;
    _Float16* Wt = (z < 3) ? WtQKV + (size_t)z * DM * HD_ : WtO;
    const int bx = blockIdx.x * 32, by = blockIdx.y * 32;
    const int tx = threadIdx.x, ty = threadIdx.y;
#pragma unroll
    for (int i = 0; i < 4; ++i)
        t[ty + 8 * i][tx] = W[(size_t)(by + ty + 8 * i) * HD_ + bx + tx];
    __syncthreads();
#pragma unroll
    for (int i = 0; i < 4; ++i)
        Wt[(size_t)(bx + ty + 8 * i) * DM + by + tx] = (_Float16)t[tx][ty + 8 * i];
}

// ---------------------------------------------------------------------------
// chunk_sums: states^T[d][i] (f16, transposed) + z row via ones-row MFMA trick
// ---------------------------------------------------------------------------
__global__ __launch_bounds__(256) void chunk_sums(
    const _Float16* __restrict__ KT, const _Float16* __restrict__ VT,
    _Float16* __restrict__ states)
{
    __shared__ char sm[26880];
    _Float16* cwh = (_Float16*)(sm);        // 64 f16
    _Float16* swh = (_Float16*)(sm + 128);
    #define CS_KC 256
    #define CS_KS 8448
    #define CS_VT 16640   // 66 rows + overrun pad inside sm

    const int c = blockIdx.x, bh = blockIdx.y;
    const int tid = threadIdx.x, lane = tid & 63, w = tid >> 6;

    if (tid < 64) {
        float s_, c_;
        sincosf(ANG_STEP * (float)(c * 64 + tid), &s_, &c_);
        cwh[tid] = (_Float16)c_; swh[tid] = (_Float16)s_;
    }
    __syncthreads();

    const size_t ktb = (size_t)(bh * 64) * TSEQ + c * 64;
#pragma unroll
    for (int rnd = 0; rnd < 2; ++rnd) {
        int lin = rnd * 256 + tid;
        int r = lin >> 3, u = lin & 7;
        h8_t kv = *(const h8_t*)(KT + ktb + (size_t)r * TSEQ + u * 8);
        h8_t c8 = *(const h8_t*)&cwh[u * 8];
        h8_t s8 = *(const h8_t*)&swh[u * 8];
        int sb = (r * 128 + u * 16) ^ ((r & 7) << 4);
        *(h8_t*)(sm + CS_KC + sb) = kv * c8;
        *(h8_t*)(sm + CS_KS + sb) = kv * s8;
    }
    const _Float16* vtb = VT + (size_t)(bh * 64) * TSEQ + c * 64;
#pragma unroll
    for (int rnd = 0; rnd < 2; ++rnd) {
        int lin = rnd * 256 + tid;
        int r = lin >> 3, u = lin & 7;
        gload16(vtb + (size_t)r * TSEQ + (u ^ (r & 7)) * 8,
                sm + CS_VT + (rnd * 256 + w * 64) * 16);
    }
    if (tid < 8) {
        h8_t one;
#pragma unroll
        for (int e = 0; e < 8; ++e) one[e] = (_Float16)1.0f;
        *(h8_t*)(sm + CS_VT + 64 * 128 + tid * 16) = one;
    }
    __syncthreads();

    const int fr = lane & 15, rm = (lane >> 4) * 4;
    _Float16* stc = states + (size_t)(bh * NCH + c) * SSTR;

    for (int half = 0; half < 2; ++half) {
        const int ko = half ? CS_KS : CS_KC;
        f32x4 acc[4][5];
#pragma unroll
        for (int i = 0; i < 4; ++i)
#pragma unroll
            for (int j = 0; j < 5; ++j) acc[i][j] = (f32x4){0.f, 0.f, 0.f, 0.f};
#pragma unroll
        for (int ks = 0; ks < 2; ++ks) {
            const int fko = ks * 64 + (lane >> 4) * 16;
            h8_t af[4], bf[5];
#pragma unroll
            for (int i = 0; i < 4; ++i) {
                int row = i * 16 + fr;
                af[i] = *(const h8_t*)(sm + ko + ((row * 128 + fko) ^ ((row & 7) << 4)));
            }
#pragma unroll
            for (int j = 0; j < 5; ++j) {
                int row = j * 16 + fr;
                bf[j] = *(const h8_t*)(sm + CS_VT + ((row * 128 + fko) ^ ((row & 7) << 4)));
            }
#pragma unroll
            for (int i = 0; i < 4; ++i)
#pragma unroll
                for (int j = 0; j < 5; ++j)
                    acc[i][j] = __builtin_amdgcn_mfma_f32_16x16x32_f16(af[i], bf[j], acc[i][j], 0, 0, 0);
        }
        _Float16* dst = stc + half * SHALF;
#pragma unroll
        for (int j = 0; j < 5; ++j) {
            int n = j * 16 + fr;
#pragma unroll
            for (int i = 0; i < 4; ++i) {
                h4_t pk;
#pragma unroll
                for (int r = 0; r < 4; ++r) pk[r] = (_Float16)acc[i][j][r];
                if (n <= 64) *(h4_t*)(dst + (size_t)n * 64 + i * 16 + rm) = pk;
            }
        }
    }
}

// ---------------------------------------------------------------------------
// exclusive prefix over chunks, f16 state, fp32 running sums. grid (5,32).
// 4x unrolled: 4 independent loads in flight per group to hide L3 latency.
// ---------------------------------------------------------------------------
__global__ __launch_bounds__(256) void scan_kernel(_Float16* __restrict__ states)
{
    const int e8 = blockIdx.x * 256 + threadIdx.x;
    if (e8 >= SSTR / 8) return;
    _Float16* p = states + (size_t)blockIdx.y * (NCH * (size_t)SSTR) + (size_t)e8 * 8;
    float run[8];
#pragma unroll
    for (int e = 0; e < 8; ++e) run[e] = 0.f;
    for (int c = 0; c < NCH; c += 4) {
        h8_t v0 = *(const h8_t*)(p + (size_t)(c + 0) * SSTR);
        h8_t v1 = *(const h8_t*)(p + (size_t)(c + 1) * SSTR);
        h8_t v2 = *(const h8_t*)(p + (size_t)(c + 2) * SSTR);
        h8_t v3 = *(const h8_t*)(p + (size_t)(c + 3) * SSTR);
        h8_t o0, o1, o2, o3;
#pragma unroll
        for (int e = 0; e < 8; ++e) {
            o0[e] = (_Float16)run[e]; run[e] += (float)v0[e];
            o1[e] = (_Float16)run[e]; run[e] += (float)v1[e];
            o2[e] = (_Float16)run[e]; run[e] += (float)v2[e];
            o3[e] = (_Float16)run[e]; run[e] += (float)v3[e];
        }
        *(h8_t*)(p + (size_t)(c + 0) * SSTR) = o0;
        *(h8_t*)(p + (size_t)(c + 1) * SSTR) = o1;
        *(h8_t*)(p + (size_t)(c + 2) * SSTR) = o2;
        *(h8_t*)(p + (size_t)(c + 3) * SSTR) = o3;
    }
}

// ---------------------------------------------------------------------------
// MFMA attention: QK^T -> mask/scale -> (A.V + Qc.Sc + Qs.Ss) with den column
// output flushed via LDS (dead AT_K region) as coalesced h8 stores.
// ---------------------------------------------------------------------------
__global__ __launch_bounds__(256) void attn_mfma(
    const _Float16* __restrict__ Qh, const _Float16* __restrict__ Kh,
    const _Float16* __restrict__ VT, const _Float16* __restrict__ states,
    _Float16* __restrict__ atth)
{
    __shared__ char sm[53248];
    float* cwf = (float*)(sm);
    float* swf = (float*)(sm + 256);
    _Float16* cwh = (_Float16*)(sm + 512);
    _Float16* swh = (_Float16*)(sm + 640);
    #define AT_Q 768
    #define AT_K 8960
    #define AT_A 17152
    #define AT_V 25344
    #define AT_C 33792
    #define AT_S 43008

    const int c = blockIdx.x, bh = blockIdx.y;
    const int b = bh >> 4, h = bh & 15;
    const int tid = threadIdx.x, lane = tid & 63, w = tid >> 6;
    const int tok0 = b * TSEQ + c * 64;

    if (tid < 64) {
        float s_, c_;
        sincosf(ANG_STEP * (float)(c * 64 + tid), &s_, &c_);
        cwf[tid] = c_; swf[tid] = s_;
        cwh[tid] = (_Float16)c_; swh[tid] = (_Float16)s_;
    }

    const _Float16* stb = states + (size_t)(bh * NCH + c) * SSTR;
#pragma unroll
    for (int rnd = 0; rnd < 2; ++rnd) {
        int lin = rnd * 256 + tid;
        int r = lin >> 3, u = lin & 7;
        int su = (u ^ (r & 7)) * 8;
        char* lb = sm + (rnd * 256 + w * 64) * 16;
        gload16(Qh + (size_t)(tok0 + r) * HD_ + h * 64 + su, lb + AT_Q);
        gload16(Kh + (size_t)(tok0 + r) * HD_ + h * 64 + su, lb + AT_K);
        gload16(VT + (size_t)(bh * 64 + r) * TSEQ + c * 64 + su, lb + AT_V);
    }
#pragma unroll
    for (int rnd = 0; rnd < 3; ++rnd) {
        if (rnd < 2 || tid < 64) {
            int lin = rnd * 256 + tid;
            int r = lin >> 3, u = lin & 7;
            int su = (u ^ (r & 7)) * 8;
            char* lb = sm + (rnd * 256 + w * 64) * 16;
            gload16(stb + (size_t)r * 64 + su, lb + AT_C);
            gload16(stb + SHALF + (size_t)r * 64 + su, lb + AT_S);
        }
    }
    if (tid < 8) {
        h8_t one;
#pragma unroll
        for (int e = 0; e < 8; ++e) one[e] = (_Float16)1.0f;
        *(h8_t*)(sm + AT_V + 64 * 128 + tid * 16) = one;
    }
    __syncthreads();

    const int fr = lane & 15;
    // ---- QK^T: D[s][tt] = K.Q^T
    f32x4 dt[4][4];
#pragma unroll
    for (int i = 0; i < 4; ++i)
#pragma unroll
        for (int j = 0; j < 4; ++j) dt[i][j] = (f32x4){0.f, 0.f, 0.f, 0.f};
#pragma unroll
    for (int ks = 0; ks < 2; ++ks) {
        const int fko = ks * 64 + (lane >> 4) * 16;
        h8_t ak[4], bq[4];
#pragma unroll
        for (int i = 0; i < 4; ++i) {
            int row = i * 16 + fr;
            int sb = (row * 128 + fko) ^ ((row & 7) << 4);
            ak[i] = *(const h8_t*)(sm + AT_K + sb);
            bq[i] = *(const h8_t*)(sm + AT_Q + sb);
        }
#pragma unroll
        for (int i = 0; i < 4; ++i)
#pragma unroll
            for (int j = 0; j < 4; ++j)
                dt[i][j] = __builtin_amdgcn_mfma_f32_16x16x32_f16(ak[i], bq[j], dt[i][j], 0, 0, 0);
    }
    // ---- mask + cos-reweight, write A[tt][s] f16 (swizzled)
    {
        const int sr0 = (lane >> 4) * 4;
#pragma unroll
        for (int j = 0; j < 4; ++j) {
            const int tt = j * 16 + fr;
            const float cwt = cwf[tt], swt = swf[tt];
#pragma unroll
            for (int i = 0; i < 4; ++i) {
                const int s0 = i * 16 + sr0;
                h4_t pk;
#pragma unroll
                for (int r = 0; r < 4; ++r) {
                    int s = s0 + r;
                    float f = cwt * cwf[s] + swt * swf[s];
                    float a = (s <= tt) ? dt[i][j][r] * f : 0.f;
                    pk[r] = (_Float16)a;
                }
                int sb = (tt * 128 + s0 * 2) ^ ((tt & 7) << 4);
                *(h4_t*)(sm + AT_A + sb) = pk;
            }
        }
    }
    __syncthreads();

    // ---- O = A.V + Qc.ScT^T + Qs.SsT^T ; col 64 = den (intra + inter)
    f32x4 o[4][5];
#pragma unroll
    for (int i = 0; i < 4; ++i)
#pragma unroll
        for (int j = 0; j < 5; ++j) o[i][j] = (f32x4){0.f, 0.f, 0.f, 0.f};
#pragma unroll
    for (int ks = 0; ks < 2; ++ks) {
        const int fko = ks * 64 + (lane >> 4) * 16;
        h8_t aa[4], aqc[4], aqs[4];
#pragma unroll
        for (int i = 0; i < 4; ++i) {
            int row = i * 16 + fr;
            int sb = (row * 128 + fko) ^ ((row & 7) << 4);
            aa[i] = *(const h8_t*)(sm + AT_A + sb);
            h8_t q8 = *(const h8_t*)(sm + AT_Q + sb);
            aqc[i] = q8 * cwh[row];
            aqs[i] = q8 * swh[row];
        }
#pragma unroll
        for (int j = 0; j < 5; ++j) {
            int row = j * 16 + fr;
            int sb = (row * 128 + fko) ^ ((row & 7) << 4);
            h8_t bv = *(const h8_t*)(sm + AT_V + sb);
            h8_t bc = *(const h8_t*)(sm + AT_C + sb);
            h8_t bs = *(const h8_t*)(sm + AT_S + sb);
#pragma unroll
            for (int i = 0; i < 4; ++i) {
                o[i][j] = __builtin_amdgcn_mfma_f32_16x16x32_f16(aa[i],  bv, o[i][j], 0, 0, 0);
                o[i][j] = __builtin_amdgcn_mfma_f32_16x16x32_f16(aqc[i], bc, o[i][j], 0, 0, 0);
                o[i][j] = __builtin_amdgcn_mfma_f32_16x16x32_f16(aqs[i], bs, o[i][j], 0, 0, 0);
            }
        }
    }
    // ---- den broadcast + LDS-staged coalesced output (reuse dead AT_K, 8KB)
    char* Ce = sm + AT_K;   // 64 t-rows x 64 d cols f16, 128B rows, swizzled
    const int rm = (lane >> 4) * 4;
#pragma unroll
    for (int i = 0; i < 4; ++i) {
        float rden[4];
#pragma unroll
        for (int r = 0; r < 4; ++r)
            rden[r] = 1.0f / fmaxf(__shfl(o[i][4][r], lane & 48), 1e-6f);
#pragma unroll
        for (int j = 0; j < 4; ++j) {
            const int col = j * 16 + fr;
#pragma unroll
            for (int r = 0; r < 4; ++r) {
                const int t = i * 16 + rm + r;
                const int byte = ((t << 7) + (col << 1)) ^ ((t & 7) << 4);
                *(_Float16*)(Ce + byte) = (_Float16)(o[i][j][r] * rden[r]);
            }
        }
    }
    __syncthreads();
#pragma unroll
    for (int p = 0; p < 2; ++p) {
        const int lin = p * 256 + tid;
        const int t = lin >> 3, d8 = lin & 7;
        h8_t v = *(const h8_t*)(Ce + (t << 7) + ((d8 ^ (t & 7)) << 4));
        *(h8_t*)(atth + (size_t)(tok0 + t) * HD_ + h * 64 + d8 * 8) = v;
    }
}

// ---------------------------------------------------------------------------
extern "C" void kernel_launch(void* const* d_in, const int* in_sizes, int n_in,
                              void* d_out, int out_size, void* d_ws, size_t ws_size,
                              hipStream_t stream)
{
    const float* x  = (const float*)d_in[0];
    const float* Wq = (const float*)d_in[1];
    const float* bq = (const float*)d_in[2];
    const float* Wk = (const float*)d_in[3];
    const float* bk = (const float*)d_in[4];
    const float* Wv = (const float*)d_in[5];
    const float* bv = (const float*)d_in[6];
    const float* Wo = (const float*)d_in[7];
    const float* bo = (const float*)d_in[8];
    float* out = (float*)d_out;

    _Float16* ws = (_Float16*)d_ws;
    _Float16* Xh     = ws;                                  // NTOK*DM
    _Float16* WtQKV  = Xh + (size_t)NTOK * DM;              // 3*DM*HD_
    _Float16* WtO    = WtQKV + 3 * (size_t)DM * HD_;        // DM*HD_
    _Float16* Qh     = WtO + (size_t)DM * HD_;              // NTOK*HD_
    _Float16* Kh     = Qh + (size_t)NTOK * HD_;
    _Float16* KT     = Kh + (size_t)NTOK * HD_;             // [bh][64][4096]
    _Float16* VT     = KT + (size_t)NTOK * HD_;
    _Float16* atth   = VT + (size_t)NTOK * HD_;
    _Float16* states = atth + (size_t)NTOK * HD_;           // 32*64*SSTR

    dim3 tb(256);
    hipLaunchKernelGGL(conv_x_kernel, dim3(NTOK * DM / 1024), tb, 0, stream, x, Xh);
    hipLaunchKernelGGL(conv_wt4, dim3(32, 32, 4), dim3(32, 8), 0, stream,
                       Wq, Wk, Wv, Wo, WtQKV, WtO);
    hipLaunchKernelGGL(gemm_qkv, dim3(192, 8), tb, 0, stream,
                       Xh, WtQKV, bq, bk, bv, Qh, Kh, KT, VT);
    hipLaunchKernelGGL(chunk_sums, dim3(NCH, 32), tb, 0, stream, KT, VT, states);
    hipLaunchKernelGGL(scan_kernel, dim3(5, 32), tb, 0, stream, states);
    hipLaunchKernelGGL(attn_mfma, dim3(NCH, 32), tb, 0, stream, Qh, Kh, VT, states, atth);
    hipLaunchKernelGGL(gemm_out, dim3(64, 8), tb, 0, stream, atth, WtO, bo, out);
}

// Round 7
// 295.592 us; speedup vs baseline: 1.0349x; 1.0349x over previous
//
#include <hip/hip_runtime.h>

#define NTOK   8192     // B*T
#define DM     1024     // d_model
#define HD_    1024     // H*dh
#define TSEQ   4096
#define NCH    64       // TSEQ / 64
#define SROWS  72       // rows per state half ([d][i] 0-63, z row 64, pad 65-71)
#define SHALF  (SROWS*64)       // 4608 f16
#define SSTR   (2*SHALF)        // 9216 f16 per (bh,c)
#define ANG_STEP 3.8349519697141029e-4f   // pi / (2*4096)

typedef _Float16 h8_t  __attribute__((ext_vector_type(8)));
typedef _Float16 h4_t  __attribute__((ext_vector_type(4)));
typedef float    f32x4 __attribute__((ext_vector_type(4)));

__device__ __forceinline__ void gload16(const void* g, void* l) {
    __builtin_amdgcn_global_load_lds(
        (const __attribute__((address_space(1))) void*)g,
        (__attribute__((address_space(3))) void*)l, 16, 0, 0);
}

// ---------------------------------------------------------------------------
// f16 MFMA GEMM core — round-3 configuration (empirically best: VGPR 80,
// 6 blocks/CU; direct-store epilogue). Do NOT LDS-stage the epilogue: R4-R6
// measured it costs occupancy (VGPR 92-100) and loses more than coalescing
// gains. Modes: 0 f16 rows+relu (Q); 1 rows+relu + [bh][d][T] packs (K);
// 2 packs only (V); 3 f32 rows (final out).
// ---------------------------------------------------------------------------
__device__ __forceinline__ void gemm_core(
    const _Float16* __restrict__ A, const _Float16* __restrict__ Wt,
    const float* __restrict__ bias, int mode,
    _Float16* rows16, _Float16* tp16, float* rows32,
    _Float16 (*As)[32], _Float16 (*Bs)[32])
{
    const int tid = threadIdx.x;
    const int lane = tid & 63, w = tid >> 6;
    const int m_base = blockIdx.x * 128, n_base = blockIdx.y * 128;

    const int r0 = tid >> 2;
    const int cb0 = (tid & 3) << 4;
    const _Float16* ga = A  + (size_t)(m_base + r0) * DM + (cb0 >> 1);
    const _Float16* gb = Wt + (size_t)(n_base + r0) * DM + (cb0 >> 1);
    char* lA = (char*)As + w * 1024;
    char* lB = (char*)Bs + w * 1024;

    f32x4 acc[4][4];
#pragma unroll
    for (int i = 0; i < 4; ++i)
#pragma unroll
        for (int j = 0; j < 4; ++j) acc[i][j] = (f32x4){0.f, 0.f, 0.f, 0.f};

    const int wm = (w >> 1) * 64, wn = (w & 1) * 64;
    const int fr = lane & 15;
    const int fk = (lane >> 4) * 16;

    for (int kt = 0; kt < DM / 32; ++kt) {
        const int k0 = kt * 32;
        __syncthreads();
        gload16(ga + k0,           lA);
        gload16(ga + 64 * DM + k0, lA + 4096);
        gload16(gb + k0,           lB);
        gload16(gb + 64 * DM + k0, lB + 4096);
        __syncthreads();
        h8_t a[4], b[4];
#pragma unroll
        for (int i = 0; i < 4; ++i) {
            a[i] = *(const h8_t*)((const char*)&As[wm + i * 16 + fr][0] + fk);
            b[i] = *(const h8_t*)((const char*)&Bs[wn + i * 16 + fr][0] + fk);
        }
#pragma unroll
        for (int i = 0; i < 4; ++i)
#pragma unroll
            for (int j = 0; j < 4; ++j)
                acc[i][j] = __builtin_amdgcn_mfma_f32_16x16x32_f16(a[i], b[j], acc[i][j], 0, 0, 0);
    }

    // D layout (verified): col = lane&15 (+j*16), row = (lane>>4)*4 + reg (+i*16)
    const int cn = lane & 15, rm = (lane >> 4) * 4;
#pragma unroll
    for (int j = 0; j < 4; ++j) {
        const int col = n_base + wn + j * 16 + cn;
        const float bs = bias[col];
#pragma unroll
        for (int i = 0; i < 4; ++i) {
            const int m0 = m_base + wm + i * 16 + rm;
            if (mode == 3) {
#pragma unroll
                for (int r = 0; r < 4; ++r)
                    rows32[(size_t)(m0 + r) * HD_ + col] = acc[i][j][r] + bs;
            } else {
                float v[4];
#pragma unroll
                for (int r = 0; r < 4; ++r) {
                    v[r] = acc[i][j][r] + bs;
                    if (mode <= 1) v[r] = fmaxf(v[r], 0.f);
                }
                if (mode <= 1) {
#pragma unroll
                    for (int r = 0; r < 4; ++r)
                        rows16[(size_t)(m0 + r) * HD_ + col] = (_Float16)v[r];
                }
                if (mode >= 1) {
                    h4_t pk;
#pragma unroll
                    for (int r = 0; r < 4; ++r) pk[r] = (_Float16)v[r];
                    const int bb = m0 >> 12, t = m0 & 4095;
                    const int hh = col >> 6, dd = col & 63;
                    *(h4_t*)(tp16 + ((size_t)(bb * 16 + hh) * 64 + dd) * TSEQ + t) = pk;
                }
            }
        }
    }
}

// z-outermost (blockIdx.z): consecutive blocks within a z-slice share the
// W-panel; X stays L2-resident per slice. (R6's z-innermost: FETCH 49->107MB.)
__global__ __launch_bounds__(256) void gemm_qkv(
    const _Float16* __restrict__ Xh, const _Float16* __restrict__ WtQKV,
    const float* __restrict__ bq, const float* __restrict__ bk, const float* __restrict__ bv,
    _Float16* __restrict__ Qh, _Float16* __restrict__ Kh,
    _Float16* __restrict__ KT, _Float16* __restrict__ VT)
{
    __shared__ _Float16 As[128][32];
    __shared__ _Float16 Bs[128][32];
    const int z = blockIdx.z;
    const _Float16* Wt = WtQKV + (size_t)z * (DM * HD_);
    const float* bias = (z == 0) ? bq : (z == 1) ? bk : bv;
    _Float16* r16 = (z == 0) ? Qh : Kh;
    _Float16* t16 = (z == 1) ? KT : VT;
    gemm_core(Xh, Wt, bias, z, r16, t16, nullptr, As, Bs);
}

__global__ __launch_bounds__(256) void gemm_out(
    const _Float16* __restrict__ A, const _Float16* __restrict__ Wt,
    const float* __restrict__ bias, float* __restrict__ out)
{
    __shared__ _Float16 As[128][32];
    __shared__ _Float16 Bs[128][32];
    gemm_core(A, Wt, bias, 3, nullptr, nullptr, out, As, Bs);
}

// ---------------------------------------------------------------------------
// converts
// ---------------------------------------------------------------------------
__global__ __launch_bounds__(256) void conv_x_kernel(
    const float* __restrict__ x, _Float16* __restrict__ xh)
{
    const int i = blockIdx.x * 256 + threadIdx.x;
    float4 v = ((const float4*)x)[i];
    h4_t hv;
    hv[0] = (_Float16)v.x; hv[1] = (_Float16)v.y;
    hv[2] = (_Float16)v.z; hv[3] = (_Float16)v.w;
    ((h4_t*)xh)[i] = hv;
}

__global__ __launch_bounds__(256) void conv_wt4(
    const float* __restrict__ Wq, const float* __restrict__ Wk,
    const float* __restrict__ Wv, const float* __restrict__ Wo,
    _Float16* __restrict__ WtQKV, _Float16* __restrict__ WtO)
{
    __shared__ float t[32][33];
    const int z = blockIdx.z;
    const float* W = (z == 0) ? Wq : (z == 1) ? Wk : (z == 2) ? Wv : Wo;
    _Float16* Wt = (z < 3) ? WtQKV + (size_t)z * DM * HD_ : WtO;
    const int bx = blockIdx.x * 32, by = blockIdx.y * 32;
    const int tx = threadIdx.x, ty = threadIdx.y;
#pragma unroll
    for (int i = 0; i < 4; ++i)
        t[ty + 8 * i][tx] = W[(size_t)(by + ty + 8 * i) * HD_ + bx + tx];
    __syncthreads();
#pragma unroll
    for (int i = 0; i < 4; ++i)
        Wt[(size_t)(bx + ty + 8 * i) * DM + by + tx] = (_Float16)t[tx][ty + 8 * i];
}

// ---------------------------------------------------------------------------
// chunk_sums: states^T[d][i] (f16, transposed) + z row via ones-row MFMA trick
// ---------------------------------------------------------------------------
__global__ __launch_bounds__(256) void chunk_sums(
    const _Float16* __restrict__ KT, const _Float16* __restrict__ VT,
    _Float16* __restrict__ states)
{
    __shared__ char sm[26880];
    _Float16* cwh = (_Float16*)(sm);        // 64 f16
    _Float16* swh = (_Float16*)(sm + 128);
    #define CS_KC 256
    #define CS_KS 8448
    #define CS_VT 16640   // 66 rows + overrun pad inside sm

    const int c = blockIdx.x, bh = blockIdx.y;
    const int tid = threadIdx.x, lane = tid & 63, w = tid >> 6;

    if (tid < 64) {
        float s_, c_;
        sincosf(ANG_STEP * (float)(c * 64 + tid), &s_, &c_);
        cwh[tid] = (_Float16)c_; swh[tid] = (_Float16)s_;
    }
    __syncthreads();

    const size_t ktb = (size_t)(bh * 64) * TSEQ + c * 64;
#pragma unroll
    for (int rnd = 0; rnd < 2; ++rnd) {
        int lin = rnd * 256 + tid;
        int r = lin >> 3, u = lin & 7;
        h8_t kv = *(const h8_t*)(KT + ktb + (size_t)r * TSEQ + u * 8);
        h8_t c8 = *(const h8_t*)&cwh[u * 8];
        h8_t s8 = *(const h8_t*)&swh[u * 8];
        int sb = (r * 128 + u * 16) ^ ((r & 7) << 4);
        *(h8_t*)(sm + CS_KC + sb) = kv * c8;
        *(h8_t*)(sm + CS_KS + sb) = kv * s8;
    }
    const _Float16* vtb = VT + (size_t)(bh * 64) * TSEQ + c * 64;
#pragma unroll
    for (int rnd = 0; rnd < 2; ++rnd) {
        int lin = rnd * 256 + tid;
        int r = lin >> 3, u = lin & 7;
        gload16(vtb + (size_t)r * TSEQ + (u ^ (r & 7)) * 8,
                sm + CS_VT + (rnd * 256 + w * 64) * 16);
    }
    if (tid < 8) {
        h8_t one;
#pragma unroll
        for (int e = 0; e < 8; ++e) one[e] = (_Float16)1.0f;
        *(h8_t*)(sm + CS_VT + 64 * 128 + tid * 16) = one;
    }
    __syncthreads();

    const int fr = lane & 15, rm = (lane >> 4) * 4;
    _Float16* stc = states + (size_t)(bh * NCH + c) * SSTR;

    for (int half = 0; half < 2; ++half) {
        const int ko = half ? CS_KS : CS_KC;
        f32x4 acc[4][5];
#pragma unroll
        for (int i = 0; i < 4; ++i)
#pragma unroll
            for (int j = 0; j < 5; ++j) acc[i][j] = (f32x4){0.f, 0.f, 0.f, 0.f};
#pragma unroll
        for (int ks = 0; ks < 2; ++ks) {
            const int fko = ks * 64 + (lane >> 4) * 16;
            h8_t af[4], bf[5];
#pragma unroll
            for (int i = 0; i < 4; ++i) {
                int row = i * 16 + fr;
                af[i] = *(const h8_t*)(sm + ko + ((row * 128 + fko) ^ ((row & 7) << 4)));
            }
#pragma unroll
            for (int j = 0; j < 5; ++j) {
                int row = j * 16 + fr;
                bf[j] = *(const h8_t*)(sm + CS_VT + ((row * 128 + fko) ^ ((row & 7) << 4)));
            }
#pragma unroll
            for (int i = 0; i < 4; ++i)
#pragma unroll
                for (int j = 0; j < 5; ++j)
                    acc[i][j] = __builtin_amdgcn_mfma_f32_16x16x32_f16(af[i], bf[j], acc[i][j], 0, 0, 0);
        }
        _Float16* dst = stc + half * SHALF;
#pragma unroll
        for (int j = 0; j < 5; ++j) {
            int n = j * 16 + fr;
#pragma unroll
            for (int i = 0; i < 4; ++i) {
                h4_t pk;
#pragma unroll
                for (int r = 0; r < 4; ++r) pk[r] = (_Float16)acc[i][j][r];
                if (n <= 64) *(h4_t*)(dst + (size_t)n * 64 + i * 16 + rm) = pk;
            }
        }
    }
}

// ---------------------------------------------------------------------------
// exclusive prefix over chunks, f16 state, fp32 running sums. grid (5,32).
// 4x unrolled: 4 independent loads in flight to hide L2/L3 latency.
// ---------------------------------------------------------------------------
__global__ __launch_bounds__(256) void scan_kernel(_Float16* __restrict__ states)
{
    const int e8 = blockIdx.x * 256 + threadIdx.x;
    if (e8 >= SSTR / 8) return;
    _Float16* p = states + (size_t)blockIdx.y * (NCH * (size_t)SSTR) + (size_t)e8 * 8;
    float run[8];
#pragma unroll
    for (int e = 0; e < 8; ++e) run[e] = 0.f;
    for (int c = 0; c < NCH; c += 4) {
        h8_t v0 = *(const h8_t*)(p + (size_t)(c + 0) * SSTR);
        h8_t v1 = *(const h8_t*)(p + (size_t)(c + 1) * SSTR);
        h8_t v2 = *(const h8_t*)(p + (size_t)(c + 2) * SSTR);
        h8_t v3 = *(const h8_t*)(p + (size_t)(c + 3) * SSTR);
        h8_t o0, o1, o2, o3;
#pragma unroll
        for (int e = 0; e < 8; ++e) {
            o0[e] = (_Float16)run[e]; run[e] += (float)v0[e];
            o1[e] = (_Float16)run[e]; run[e] += (float)v1[e];
            o2[e] = (_Float16)run[e]; run[e] += (float)v2[e];
            o3[e] = (_Float16)run[e]; run[e] += (float)v3[e];
        }
        *(h8_t*)(p + (size_t)(c + 0) * SSTR) = o0;
        *(h8_t*)(p + (size_t)(c + 1) * SSTR) = o1;
        *(h8_t*)(p + (size_t)(c + 2) * SSTR) = o2;
        *(h8_t*)(p + (size_t)(c + 3) * SSTR) = o3;
    }
}

// ---------------------------------------------------------------------------
// MFMA attention: QK^T -> mask/scale -> (A.V + Qc.Sc + Qs.Ss) with den column
// output flushed via LDS (dead AT_K region) as coalesced h8 stores.
// ---------------------------------------------------------------------------
__global__ __launch_bounds__(256) void attn_mfma(
    const _Float16* __restrict__ Qh, const _Float16* __restrict__ Kh,
    const _Float16* __restrict__ VT, const _Float16* __restrict__ states,
    _Float16* __restrict__ atth)
{
    __shared__ char sm[53248];
    float* cwf = (float*)(sm);
    float* swf = (float*)(sm + 256);
    _Float16* cwh = (_Float16*)(sm + 512);
    _Float16* swh = (_Float16*)(sm + 640);
    #define AT_Q 768
    #define AT_K 8960
    #define AT_A 17152
    #define AT_V 25344
    #define AT_C 33792
    #define AT_S 43008

    const int c = blockIdx.x, bh = blockIdx.y;
    const int b = bh >> 4, h = bh & 15;
    const int tid = threadIdx.x, lane = tid & 63, w = tid >> 6;
    const int tok0 = b * TSEQ + c * 64;

    if (tid < 64) {
        float s_, c_;
        sincosf(ANG_STEP * (float)(c * 64 + tid), &s_, &c_);
        cwf[tid] = c_; swf[tid] = s_;
        cwh[tid] = (_Float16)c_; swh[tid] = (_Float16)s_;
    }

    const _Float16* stb = states + (size_t)(bh * NCH + c) * SSTR;
#pragma unroll
    for (int rnd = 0; rnd < 2; ++rnd) {
        int lin = rnd * 256 + tid;
        int r = lin >> 3, u = lin & 7;
        int su = (u ^ (r & 7)) * 8;
        char* lb = sm + (rnd * 256 + w * 64) * 16;
        gload16(Qh + (size_t)(tok0 + r) * HD_ + h * 64 + su, lb + AT_Q);
        gload16(Kh + (size_t)(tok0 + r) * HD_ + h * 64 + su, lb + AT_K);
        gload16(VT + (size_t)(bh * 64 + r) * TSEQ + c * 64 + su, lb + AT_V);
    }
#pragma unroll
    for (int rnd = 0; rnd < 3; ++rnd) {
        if (rnd < 2 || tid < 64) {
            int lin = rnd * 256 + tid;
            int r = lin >> 3, u = lin & 7;
            int su = (u ^ (r & 7)) * 8;
            char* lb = sm + (rnd * 256 + w * 64) * 16;
            gload16(stb + (size_t)r * 64 + su, lb + AT_C);
            gload16(stb + SHALF + (size_t)r * 64 + su, lb + AT_S);
        }
    }
    if (tid < 8) {
        h8_t one;
#pragma unroll
        for (int e = 0; e < 8; ++e) one[e] = (_Float16)1.0f;
        *(h8_t*)(sm + AT_V + 64 * 128 + tid * 16) = one;
    }
    __syncthreads();

    const int fr = lane & 15;
    // ---- QK^T: D[s][tt] = K.Q^T
    f32x4 dt[4][4];
#pragma unroll
    for (int i = 0; i < 4; ++i)
#pragma unroll
        for (int j = 0; j < 4; ++j) dt[i][j] = (f32x4){0.f, 0.f, 0.f, 0.f};
#pragma unroll
    for (int ks = 0; ks < 2; ++ks) {
        const int fko = ks * 64 + (lane >> 4) * 16;
        h8_t ak[4], bq[4];
#pragma unroll
        for (int i = 0; i < 4; ++i) {
            int row = i * 16 + fr;
            int sb = (row * 128 + fko) ^ ((row & 7) << 4);
            ak[i] = *(const h8_t*)(sm + AT_K + sb);
            bq[i] = *(const h8_t*)(sm + AT_Q + sb);
        }
#pragma unroll
        for (int i = 0; i < 4; ++i)
#pragma unroll
            for (int j = 0; j < 4; ++j)
                dt[i][j] = __builtin_amdgcn_mfma_f32_16x16x32_f16(ak[i], bq[j], dt[i][j], 0, 0, 0);
    }
    // ---- mask + cos-reweight, write A[tt][s] f16 (swizzled)
    {
        const int sr0 = (lane >> 4) * 4;
#pragma unroll
        for (int j = 0; j < 4; ++j) {
            const int tt = j * 16 + fr;
            const float cwt = cwf[tt], swt = swf[tt];
#pragma unroll
            for (int i = 0; i < 4; ++i) {
                const int s0 = i * 16 + sr0;
                h4_t pk;
#pragma unroll
                for (int r = 0; r < 4; ++r) {
                    int s = s0 + r;
                    float f = cwt * cwf[s] + swt * swf[s];
                    float a = (s <= tt) ? dt[i][j][r] * f : 0.f;
                    pk[r] = (_Float16)a;
                }
                int sb = (tt * 128 + s0 * 2) ^ ((tt & 7) << 4);
                *(h4_t*)(sm + AT_A + sb) = pk;
            }
        }
    }
    __syncthreads();

    // ---- O = A.V + Qc.ScT^T + Qs.SsT^T ; col 64 = den (intra + inter)
    f32x4 o[4][5];
#pragma unroll
    for (int i = 0; i < 4; ++i)
#pragma unroll
        for (int j = 0; j < 5; ++j) o[i][j] = (f32x4){0.f, 0.f, 0.f, 0.f};
#pragma unroll
    for (int ks = 0; ks < 2; ++ks) {
        const int fko = ks * 64 + (lane >> 4) * 16;
        h8_t aa[4], aqc[4], aqs[4];
#pragma unroll
        for (int i = 0; i < 4; ++i) {
            int row = i * 16 + fr;
            int sb = (row * 128 + fko) ^ ((row & 7) << 4);
            aa[i] = *(const h8_t*)(sm + AT_A + sb);
            h8_t q8 = *(const h8_t*)(sm + AT_Q + sb);
            aqc[i] = q8 * cwh[row];
            aqs[i] = q8 * swh[row];
        }
#pragma unroll
        for (int j = 0; j < 5; ++j) {
            int row = j * 16 + fr;
            int sb = (row * 128 + fko) ^ ((row & 7) << 4);
            h8_t bv = *(const h8_t*)(sm + AT_V + sb);
            h8_t bc = *(const h8_t*)(sm + AT_C + sb);
            h8_t bs = *(const h8_t*)(sm + AT_S + sb);
#pragma unroll
            for (int i = 0; i < 4; ++i) {
                o[i][j] = __builtin_amdgcn_mfma_f32_16x16x32_f16(aa[i],  bv, o[i][j], 0, 0, 0);
                o[i][j] = __builtin_amdgcn_mfma_f32_16x16x32_f16(aqc[i], bc, o[i][j], 0, 0, 0);
                o[i][j] = __builtin_amdgcn_mfma_f32_16x16x32_f16(aqs[i], bs, o[i][j], 0, 0, 0);
            }
        }
    }
    // ---- den broadcast + LDS-staged coalesced output (reuse dead AT_K, 8KB)
    char* Ce = sm + AT_K;   // 64 t-rows x 64 d cols f16, 128B rows, swizzled
    const int rm = (lane >> 4) * 4;
#pragma unroll
    for (int i = 0; i < 4; ++i) {
        float rden[4];
#pragma unroll
        for (int r = 0; r < 4; ++r)
            rden[r] = 1.0f / fmaxf(__shfl(o[i][4][r], lane & 48), 1e-6f);
#pragma unroll
        for (int j = 0; j < 4; ++j) {
            const int col = j * 16 + fr;
#pragma unroll
            for (int r = 0; r < 4; ++r) {
                const int t = i * 16 + rm + r;
                const int byte = ((t << 7) + (col << 1)) ^ ((t & 7) << 4);
                *(_Float16*)(Ce + byte) = (_Float16)(o[i][j][r] * rden[r]);
            }
        }
    }
    __syncthreads();
#pragma unroll
    for (int p = 0; p < 2; ++p) {
        const int lin = p * 256 + tid;
        const int t = lin >> 3, d8 = lin & 7;
        h8_t v = *(const h8_t*)(Ce + (t << 7) + ((d8 ^ (t & 7)) << 4));
        *(h8_t*)(atth + (size_t)(tok0 + t) * HD_ + h * 64 + d8 * 8) = v;
    }
}

// ---------------------------------------------------------------------------
extern "C" void kernel_launch(void* const* d_in, const int* in_sizes, int n_in,
                              void* d_out, int out_size, void* d_ws, size_t ws_size,
                              hipStream_t stream)
{
    const float* x  = (const float*)d_in[0];
    const float* Wq = (const float*)d_in[1];
    const float* bq = (const float*)d_in[2];
    const float* Wk = (const float*)d_in[3];
    const float* bk = (const float*)d_in[4];
    const float* Wv = (const float*)d_in[5];
    const float* bv = (const float*)d_in[6];
    const float* Wo = (const float*)d_in[7];
    const float* bo = (const float*)d_in[8];
    float* out = (float*)d_out;

    _Float16* ws = (_Float16*)d_ws;
    _Float16* Xh     = ws;                                  // NTOK*DM
    _Float16* WtQKV  = Xh + (size_t)NTOK * DM;              // 3*DM*HD_
    _Float16* WtO    = WtQKV + 3 * (size_t)DM * HD_;        // DM*HD_
    _Float16* Qh     = WtO + (size_t)DM * HD_;              // NTOK*HD_
    _Float16* Kh     = Qh + (size_t)NTOK * HD_;
    _Float16* KT     = Kh + (size_t)NTOK * HD_;             // [bh][64][4096]
    _Float16* VT     = KT + (size_t)NTOK * HD_;
    _Float16* atth   = VT + (size_t)NTOK * HD_;
    _Float16* states = atth + (size_t)NTOK * HD_;           // 32*64*SSTR

    dim3 tb(256);
    hipLaunchKernelGGL(conv_x_kernel, dim3(NTOK * DM / 1024), tb, 0, stream, x, Xh);
    hipLaunchKernelGGL(conv_wt4, dim3(32, 32, 4), dim3(32, 8), 0, stream,
                       Wq, Wk, Wv, Wo, WtQKV, WtO);
    hipLaunchKernelGGL(gemm_qkv, dim3(64, 8, 3), tb, 0, stream,
                       Xh, WtQKV, bq, bk, bv, Qh, Kh, KT, VT);
    hipLaunchKernelGGL(chunk_sums, dim3(NCH, 32), tb, 0, stream, KT, VT, states);
    hipLaunchKernelGGL(scan_kernel, dim3(5, 32), tb, 0, stream, states);
    hipLaunchKernelGGL(attn_mfma, dim3(NCH, 32), tb, 0, stream, Qh, Kh, VT, states, atth);
    hipLaunchKernelGGL(gemm_out, dim3(64, 8), tb, 0, stream, atth, WtO, bo, out);
}

// Round 8
// 262.738 us; speedup vs baseline: 1.1643x; 1.1250x over previous
//
#include <hip/hip_runtime.h>

#define NTOK   8192     // B*T
#define DM     1024     // d_model
#define HD_    1024     // H*dh
#define TSEQ   4096
#define NCH    64       // TSEQ / 64
#define SROWS  72       // rows per state half ([d][i] 0-63, z row 64, pad 65-71)
#define SHALF  (SROWS*64)       // 4608 f16
#define SSTR   (2*SHALF)        // 9216 f16 per (bh,c)
#define ANG_STEP 3.8349519697141029e-4f   // pi / (2*4096)

typedef _Float16 h8_t  __attribute__((ext_vector_type(8)));
typedef _Float16 h4_t  __attribute__((ext_vector_type(4)));
typedef float    f32x4 __attribute__((ext_vector_type(4)));

__device__ __forceinline__ void gload16(const void* g, void* l) {
    __builtin_amdgcn_global_load_lds(
        (const __attribute__((address_space(1))) void*)g,
        (__attribute__((address_space(3))) void*)l, 16, 0, 0);
}

// ---------------------------------------------------------------------------
// f16 MFMA GEMM core — round-3 configuration (empirically best: VGPR 80,
// 6 blocks/CU; direct-store epilogue). Modes: 0 f16 rows+relu (Q);
// 1 rows+relu + [bh][d][T] packs (K); 2 packs only (V); 3 f32 rows (out).
// ---------------------------------------------------------------------------
__device__ __forceinline__ void gemm_core(
    const _Float16* __restrict__ A, const _Float16* __restrict__ Wt,
    const float* __restrict__ bias, int mode,
    _Float16* rows16, _Float16* tp16, float* rows32,
    _Float16 (*As)[32], _Float16 (*Bs)[32])
{
    const int tid = threadIdx.x;
    const int lane = tid & 63, w = tid >> 6;
    const int m_base = blockIdx.x * 128, n_base = blockIdx.y * 128;

    const int r0 = tid >> 2;
    const int cb0 = (tid & 3) << 4;
    const _Float16* ga = A  + (size_t)(m_base + r0) * DM + (cb0 >> 1);
    const _Float16* gb = Wt + (size_t)(n_base + r0) * DM + (cb0 >> 1);
    char* lA = (char*)As + w * 1024;
    char* lB = (char*)Bs + w * 1024;

    f32x4 acc[4][4];
#pragma unroll
    for (int i = 0; i < 4; ++i)
#pragma unroll
        for (int j = 0; j < 4; ++j) acc[i][j] = (f32x4){0.f, 0.f, 0.f, 0.f};

    const int wm = (w >> 1) * 64, wn = (w & 1) * 64;
    const int fr = lane & 15;
    const int fk = (lane >> 4) * 16;

    for (int kt = 0; kt < DM / 32; ++kt) {
        const int k0 = kt * 32;
        __syncthreads();
        gload16(ga + k0,           lA);
        gload16(ga + 64 * DM + k0, lA + 4096);
        gload16(gb + k0,           lB);
        gload16(gb + 64 * DM + k0, lB + 4096);
        __syncthreads();
        h8_t a[4], b[4];
#pragma unroll
        for (int i = 0; i < 4; ++i) {
            a[i] = *(const h8_t*)((const char*)&As[wm + i * 16 + fr][0] + fk);
            b[i] = *(const h8_t*)((const char*)&Bs[wn + i * 16 + fr][0] + fk);
        }
#pragma unroll
        for (int i = 0; i < 4; ++i)
#pragma unroll
            for (int j = 0; j < 4; ++j)
                acc[i][j] = __builtin_amdgcn_mfma_f32_16x16x32_f16(a[i], b[j], acc[i][j], 0, 0, 0);
    }

    // D layout (verified): col = lane&15 (+j*16), row = (lane>>4)*4 + reg (+i*16)
    const int cn = lane & 15, rm = (lane >> 4) * 4;
#pragma unroll
    for (int j = 0; j < 4; ++j) {
        const int col = n_base + wn + j * 16 + cn;
        const float bs = bias[col];
#pragma unroll
        for (int i = 0; i < 4; ++i) {
            const int m0 = m_base + wm + i * 16 + rm;
            if (mode == 3) {
#pragma unroll
                for (int r = 0; r < 4; ++r)
                    rows32[(size_t)(m0 + r) * HD_ + col] = acc[i][j][r] + bs;
            } else {
                float v[4];
#pragma unroll
                for (int r = 0; r < 4; ++r) {
                    v[r] = acc[i][j][r] + bs;
                    if (mode <= 1) v[r] = fmaxf(v[r], 0.f);
                }
                if (mode <= 1) {
#pragma unroll
                    for (int r = 0; r < 4; ++r)
                        rows16[(size_t)(m0 + r) * HD_ + col] = (_Float16)v[r];
                }
                if (mode >= 1) {
                    h4_t pk;
#pragma unroll
                    for (int r = 0; r < 4; ++r) pk[r] = (_Float16)v[r];
                    const int bb = m0 >> 12, t = m0 & 4095;
                    const int hh = col >> 6, dd = col & 63;
                    *(h4_t*)(tp16 + ((size_t)(bb * 16 + hh) * 64 + dd) * TSEQ + t) = pk;
                }
            }
        }
    }
}

// z-outermost (blockIdx.z): consecutive blocks within a z-slice share the
// W-panel; X stays L2-resident per slice. (R6's z-innermost: FETCH 49->107MB.)
__global__ __launch_bounds__(256) void gemm_qkv(
    const _Float16* __restrict__ Xh, const _Float16* __restrict__ WtQKV,
    const float* __restrict__ bq, const float* __restrict__ bk, const float* __restrict__ bv,
    _Float16* __restrict__ Qh, _Float16* __restrict__ Kh,
    _Float16* __restrict__ KT, _Float16* __restrict__ VT)
{
    __shared__ _Float16 As[128][32];
    __shared__ _Float16 Bs[128][32];
    const int z = blockIdx.z;
    const _Float16* Wt = WtQKV + (size_t)z * (DM * HD_);
    const float* bias = (z == 0) ? bq : (z == 1) ? bk : bv;
    _Float16* r16 = (z == 0) ? Qh : Kh;
    _Float16* t16 = (z == 1) ? KT : VT;
    gemm_core(Xh, Wt, bias, z, r16, t16, nullptr, As, Bs);
}

__global__ __launch_bounds__(256) void gemm_out(
    const _Float16* __restrict__ A, const _Float16* __restrict__ Wt,
    const float* __restrict__ bias, float* __restrict__ out)
{
    __shared__ _Float16 As[128][32];
    __shared__ _Float16 Bs[128][32];
    gemm_core(A, Wt, bias, 3, nullptr, nullptr, out, As, Bs);
}

// ---------------------------------------------------------------------------
// converts
// ---------------------------------------------------------------------------
__global__ __launch_bounds__(256) void conv_x_kernel(
    const float* __restrict__ x, _Float16* __restrict__ xh)
{
    const int i = blockIdx.x * 256 + threadIdx.x;
    float4 v = ((const float4*)x)[i];
    h4_t hv;
    hv[0] = (_Float16)v.x; hv[1] = (_Float16)v.y;
    hv[2] = (_Float16)v.z; hv[3] = (_Float16)v.w;
    ((h4_t*)xh)[i] = hv;
}

__global__ __launch_bounds__(256) void conv_wt4(
    const float* __restrict__ Wq, const float* __restrict__ Wk,
    const float* __restrict__ Wv, const float* __restrict__ Wo,
    _Float16* __restrict__ WtQKV, _Float16* __restrict__ WtO)
{
    __shared__ float t[32][33];
    const int z = blockIdx.z;
    const float* W = (z == 0) ? Wq : (z == 1) ? Wk : (z == 2) ? Wv : Wo;
    _Float16* Wt = (z < 3) ? WtQKV + (size_t)z * DM * HD_ : WtO;
    const int bx = blockIdx.x * 32, by = blockIdx.y * 32;
    const int tx = threadIdx.x, ty = threadIdx.y;
#pragma unroll
    for (int i = 0; i < 4; ++i)
        t[ty + 8 * i][tx] = W[(size_t)(by + ty + 8 * i) * HD_ + bx + tx];
    __syncthreads();
#pragma unroll
    for (int i = 0; i < 4; ++i)
        Wt[(size_t)(bx + ty + 8 * i) * DM + by + tx] = (_Float16)t[tx][ty + 8 * i];
}

// ---------------------------------------------------------------------------
// chunk_sums: states^T (f16) + z row via ones-row MFMA trick.
// WAVE-DISTRIBUTED: wave w owns m-frag i=w (was: all 4 waves computed all
// 4x5 fragments redundantly + same-address stores).
// ---------------------------------------------------------------------------
__global__ __launch_bounds__(256) void chunk_sums(
    const _Float16* __restrict__ KT, const _Float16* __restrict__ VT,
    _Float16* __restrict__ states)
{
    __shared__ char sm[26880];
    _Float16* cwh = (_Float16*)(sm);        // 64 f16
    _Float16* swh = (_Float16*)(sm + 128);
    #define CS_KC 256
    #define CS_KS 8448
    #define CS_VT 16640   // 66 rows + overrun pad inside sm

    const int c = blockIdx.x, bh = blockIdx.y;
    const int tid = threadIdx.x, lane = tid & 63, w = tid >> 6;

    if (tid < 64) {
        float s_, c_;
        sincosf(ANG_STEP * (float)(c * 64 + tid), &s_, &c_);
        cwh[tid] = (_Float16)c_; swh[tid] = (_Float16)s_;
    }
    __syncthreads();

    const size_t ktb = (size_t)(bh * 64) * TSEQ + c * 64;
#pragma unroll
    for (int rnd = 0; rnd < 2; ++rnd) {
        int lin = rnd * 256 + tid;
        int r = lin >> 3, u = lin & 7;
        h8_t kv = *(const h8_t*)(KT + ktb + (size_t)r * TSEQ + u * 8);
        h8_t c8 = *(const h8_t*)&cwh[u * 8];
        h8_t s8 = *(const h8_t*)&swh[u * 8];
        int sb = (r * 128 + u * 16) ^ ((r & 7) << 4);
        *(h8_t*)(sm + CS_KC + sb) = kv * c8;
        *(h8_t*)(sm + CS_KS + sb) = kv * s8;
    }
    const _Float16* vtb = VT + (size_t)(bh * 64) * TSEQ + c * 64;
#pragma unroll
    for (int rnd = 0; rnd < 2; ++rnd) {
        int lin = rnd * 256 + tid;
        int r = lin >> 3, u = lin & 7;
        gload16(vtb + (size_t)r * TSEQ + (u ^ (r & 7)) * 8,
                sm + CS_VT + (rnd * 256 + w * 64) * 16);
    }
    if (tid < 8) {
        h8_t one;
#pragma unroll
        for (int e = 0; e < 8; ++e) one[e] = (_Float16)1.0f;
        *(h8_t*)(sm + CS_VT + 64 * 128 + tid * 16) = one;
    }
    __syncthreads();

    const int fr = lane & 15, rm = (lane >> 4) * 4;
    _Float16* stc = states + (size_t)(bh * NCH + c) * SSTR;
    const int rowA = w * 16 + fr;          // this wave's m-frag rows (d_k)

    for (int half = 0; half < 2; ++half) {
        const int ko = half ? CS_KS : CS_KC;
        f32x4 acc[5];
#pragma unroll
        for (int j = 0; j < 5; ++j) acc[j] = (f32x4){0.f, 0.f, 0.f, 0.f};
#pragma unroll
        for (int ks = 0; ks < 2; ++ks) {
            const int fko = ks * 64 + (lane >> 4) * 16;
            h8_t af = *(const h8_t*)(sm + ko + ((rowA * 128 + fko) ^ ((rowA & 7) << 4)));
            h8_t bf[5];
#pragma unroll
            for (int j = 0; j < 5; ++j) {
                int row = j * 16 + fr;
                bf[j] = *(const h8_t*)(sm + CS_VT + ((row * 128 + fko) ^ ((row & 7) << 4)));
            }
#pragma unroll
            for (int j = 0; j < 5; ++j)
                acc[j] = __builtin_amdgcn_mfma_f32_16x16x32_f16(af, bf[j], acc[j], 0, 0, 0);
        }
        _Float16* dst = stc + half * SHALF;
#pragma unroll
        for (int j = 0; j < 5; ++j) {
            int n = j * 16 + fr;
            h4_t pk;
#pragma unroll
            for (int r = 0; r < 4; ++r) pk[r] = (_Float16)acc[j][r];
            if (n <= 64) *(h4_t*)(dst + (size_t)n * 64 + w * 16 + rm) = pk;
        }
    }
}

// ---------------------------------------------------------------------------
// exclusive prefix over chunks, f16 state, fp32 running sums. grid (5,32).
// 4x unrolled: 4 independent loads in flight to hide L2/L3 latency.
// ---------------------------------------------------------------------------
__global__ __launch_bounds__(256) void scan_kernel(_Float16* __restrict__ states)
{
    const int e8 = blockIdx.x * 256 + threadIdx.x;
    if (e8 >= SSTR / 8) return;
    _Float16* p = states + (size_t)blockIdx.y * (NCH * (size_t)SSTR) + (size_t)e8 * 8;
    float run[8];
#pragma unroll
    for (int e = 0; e < 8; ++e) run[e] = 0.f;
    for (int c = 0; c < NCH; c += 4) {
        h8_t v0 = *(const h8_t*)(p + (size_t)(c + 0) * SSTR);
        h8_t v1 = *(const h8_t*)(p + (size_t)(c + 1) * SSTR);
        h8_t v2 = *(const h8_t*)(p + (size_t)(c + 2) * SSTR);
        h8_t v3 = *(const h8_t*)(p + (size_t)(c + 3) * SSTR);
        h8_t o0, o1, o2, o3;
#pragma unroll
        for (int e = 0; e < 8; ++e) {
            o0[e] = (_Float16)run[e]; run[e] += (float)v0[e];
            o1[e] = (_Float16)run[e]; run[e] += (float)v1[e];
            o2[e] = (_Float16)run[e]; run[e] += (float)v2[e];
            o3[e] = (_Float16)run[e]; run[e] += (float)v3[e];
        }
        *(h8_t*)(p + (size_t)(c + 0) * SSTR) = o0;
        *(h8_t*)(p + (size_t)(c + 1) * SSTR) = o1;
        *(h8_t*)(p + (size_t)(c + 2) * SSTR) = o2;
        *(h8_t*)(p + (size_t)(c + 3) * SSTR) = o3;
    }
}

// ---------------------------------------------------------------------------
// MFMA attention. WAVE-DISTRIBUTED (was 4x redundant):
//   QK^T: wave w computes n-quadrant j=w (tt rows w*16+fr), 8 MFMA/wave.
//   PV:   wave w computes m-frag i=w (its own tt rows), 30 MFMA/wave.
// Output flushed via LDS (dead AT_K region) as coalesced h8 stores.
// ---------------------------------------------------------------------------
__global__ __launch_bounds__(256) void attn_mfma(
    const _Float16* __restrict__ Qh, const _Float16* __restrict__ Kh,
    const _Float16* __restrict__ VT, const _Float16* __restrict__ states,
    _Float16* __restrict__ atth)
{
    __shared__ char sm[53248];
    float* cwf = (float*)(sm);
    float* swf = (float*)(sm + 256);
    _Float16* cwh = (_Float16*)(sm + 512);
    _Float16* swh = (_Float16*)(sm + 640);
    #define AT_Q 768
    #define AT_K 8960
    #define AT_A 17152
    #define AT_V 25344
    #define AT_C 33792
    #define AT_S 43008

    const int c = blockIdx.x, bh = blockIdx.y;
    const int b = bh >> 4, h = bh & 15;
    const int tid = threadIdx.x, lane = tid & 63, w = tid >> 6;
    const int tok0 = b * TSEQ + c * 64;

    if (tid < 64) {
        float s_, c_;
        sincosf(ANG_STEP * (float)(c * 64 + tid), &s_, &c_);
        cwf[tid] = c_; swf[tid] = s_;
        cwh[tid] = (_Float16)c_; swh[tid] = (_Float16)s_;
    }

    const _Float16* stb = states + (size_t)(bh * NCH + c) * SSTR;
#pragma unroll
    for (int rnd = 0; rnd < 2; ++rnd) {
        int lin = rnd * 256 + tid;
        int r = lin >> 3, u = lin & 7;
        int su = (u ^ (r & 7)) * 8;
        char* lb = sm + (rnd * 256 + w * 64) * 16;
        gload16(Qh + (size_t)(tok0 + r) * HD_ + h * 64 + su, lb + AT_Q);
        gload16(Kh + (size_t)(tok0 + r) * HD_ + h * 64 + su, lb + AT_K);
        gload16(VT + (size_t)(bh * 64 + r) * TSEQ + c * 64 + su, lb + AT_V);
    }
#pragma unroll
    for (int rnd = 0; rnd < 3; ++rnd) {
        if (rnd < 2 || tid < 64) {
            int lin = rnd * 256 + tid;
            int r = lin >> 3, u = lin & 7;
            int su = (u ^ (r & 7)) * 8;
            char* lb = sm + (rnd * 256 + w * 64) * 16;
            gload16(stb + (size_t)r * 64 + su, lb + AT_C);
            gload16(stb + SHALF + (size_t)r * 64 + su, lb + AT_S);
        }
    }
    if (tid < 8) {
        h8_t one;
#pragma unroll
        for (int e = 0; e < 8; ++e) one[e] = (_Float16)1.0f;
        *(h8_t*)(sm + AT_V + 64 * 128 + tid * 16) = one;
    }
    __syncthreads();

    const int fr = lane & 15;
    const int ttw = w * 16 + fr;           // this wave's tt rows
    // ---- QK^T: D[s][tt], wave w computes n-frag j=w only
    f32x4 dt[4];
#pragma unroll
    for (int i = 0; i < 4; ++i) dt[i] = (f32x4){0.f, 0.f, 0.f, 0.f};
#pragma unroll
    for (int ks = 0; ks < 2; ++ks) {
        const int fko = ks * 64 + (lane >> 4) * 16;
        h8_t bqw = *(const h8_t*)(sm + AT_Q + ((ttw * 128 + fko) ^ ((ttw & 7) << 4)));
        h8_t ak[4];
#pragma unroll
        for (int i = 0; i < 4; ++i) {
            int row = i * 16 + fr;
            ak[i] = *(const h8_t*)(sm + AT_K + ((row * 128 + fko) ^ ((row & 7) << 4)));
        }
#pragma unroll
        for (int i = 0; i < 4; ++i)
            dt[i] = __builtin_amdgcn_mfma_f32_16x16x32_f16(ak[i], bqw, dt[i], 0, 0, 0);
    }
    // ---- mask + cos-reweight, write A[tt][s] f16 (swizzled); tt rows = wave's
    {
        const int sr0 = (lane >> 4) * 4;
        const float cwt = cwf[ttw], swt = swf[ttw];
#pragma unroll
        for (int i = 0; i < 4; ++i) {
            const int s0 = i * 16 + sr0;
            h4_t pk;
#pragma unroll
            for (int r = 0; r < 4; ++r) {
                int s = s0 + r;
                float f = cwt * cwf[s] + swt * swf[s];
                float a = (s <= ttw) ? dt[i][r] * f : 0.f;
                pk[r] = (_Float16)a;
            }
            int sb = (ttw * 128 + s0 * 2) ^ ((ttw & 7) << 4);
            *(h4_t*)(sm + AT_A + sb) = pk;
        }
    }
    __syncthreads();

    // ---- O = A.V + Qc.ScT^T + Qs.SsT^T ; col 64 = den. Wave w: m-frag i=w.
    f32x4 o[5];
#pragma unroll
    for (int j = 0; j < 5; ++j) o[j] = (f32x4){0.f, 0.f, 0.f, 0.f};
#pragma unroll
    for (int ks = 0; ks < 2; ++ks) {
        const int fko = ks * 64 + (lane >> 4) * 16;
        const int sbA = (ttw * 128 + fko) ^ ((ttw & 7) << 4);
        h8_t aa = *(const h8_t*)(sm + AT_A + sbA);
        h8_t q8 = *(const h8_t*)(sm + AT_Q + sbA);
        h8_t aqc = q8 * cwh[ttw];
        h8_t aqs = q8 * swh[ttw];
#pragma unroll
        for (int j = 0; j < 5; ++j) {
            int row = j * 16 + fr;
            int sb = (row * 128 + fko) ^ ((row & 7) << 4);
            h8_t bv = *(const h8_t*)(sm + AT_V + sb);
            h8_t bc = *(const h8_t*)(sm + AT_C + sb);
            h8_t bs = *(const h8_t*)(sm + AT_S + sb);
            o[j] = __builtin_amdgcn_mfma_f32_16x16x32_f16(aa,  bv, o[j], 0, 0, 0);
            o[j] = __builtin_amdgcn_mfma_f32_16x16x32_f16(aqc, bc, o[j], 0, 0, 0);
            o[j] = __builtin_amdgcn_mfma_f32_16x16x32_f16(aqs, bs, o[j], 0, 0, 0);
        }
    }
    // ---- den broadcast + LDS-staged coalesced output (reuse dead AT_K, 8KB)
    char* Ce = sm + AT_K;   // 64 t-rows x 64 d cols f16, 128B rows, swizzled
    const int rm = (lane >> 4) * 4;
    {
        float rden[4];
#pragma unroll
        for (int r = 0; r < 4; ++r)
            rden[r] = 1.0f / fmaxf(__shfl(o[4][r], lane & 48), 1e-6f);
#pragma unroll
        for (int j = 0; j < 4; ++j) {
            const int col = j * 16 + fr;
#pragma unroll
            for (int r = 0; r < 4; ++r) {
                const int t = w * 16 + rm + r;
                const int byte = ((t << 7) + (col << 1)) ^ ((t & 7) << 4);
                *(_Float16*)(Ce + byte) = (_Float16)(o[j][r] * rden[r]);
            }
        }
    }
    __syncthreads();
#pragma unroll
    for (int p = 0; p < 2; ++p) {
        const int lin = p * 256 + tid;
        const int t = lin >> 3, d8 = lin & 7;
        h8_t v = *(const h8_t*)(Ce + (t << 7) + ((d8 ^ (t & 7)) << 4));
        *(h8_t*)(atth + (size_t)(tok0 + t) * HD_ + h * 64 + d8 * 8) = v;
    }
}

// ---------------------------------------------------------------------------
extern "C" void kernel_launch(void* const* d_in, const int* in_sizes, int n_in,
                              void* d_out, int out_size, void* d_ws, size_t ws_size,
                              hipStream_t stream)
{
    const float* x  = (const float*)d_in[0];
    const float* Wq = (const float*)d_in[1];
    const float* bq = (const float*)d_in[2];
    const float* Wk = (const float*)d_in[3];
    const float* bk = (const float*)d_in[4];
    const float* Wv = (const float*)d_in[5];
    const float* bv = (const float*)d_in[6];
    const float* Wo = (const float*)d_in[7];
    const float* bo = (const float*)d_in[8];
    float* out = (float*)d_out;

    _Float16* ws = (_Float16*)d_ws;
    _Float16* Xh     = ws;                                  // NTOK*DM
    _Float16* WtQKV  = Xh + (size_t)NTOK * DM;              // 3*DM*HD_
    _Float16* WtO    = WtQKV + 3 * (size_t)DM * HD_;        // DM*HD_
    _Float16* Qh     = WtO + (size_t)DM * HD_;              // NTOK*HD_
    _Float16* Kh     = Qh + (size_t)NTOK * HD_;
    _Float16* KT     = Kh + (size_t)NTOK * HD_;             // [bh][64][4096]
    _Float16* VT     = KT + (size_t)NTOK * HD_;
    _Float16* atth   = VT + (size_t)NTOK * HD_;
    _Float16* states = atth + (size_t)NTOK * HD_;           // 32*64*SSTR

    dim3 tb(256);
    hipLaunchKernelGGL(conv_x_kernel, dim3(NTOK * DM / 1024), tb, 0, stream, x, Xh);
    hipLaunchKernelGGL(conv_wt4, dim3(32, 32, 4), dim3(32, 8), 0, stream,
                       Wq, Wk, Wv, Wo, WtQKV, WtO);
    hipLaunchKernelGGL(gemm_qkv, dim3(64, 8, 3), tb, 0, stream,
                       Xh, WtQKV, bq, bk, bv, Qh, Kh, KT, VT);
    hipLaunchKernelGGL(chunk_sums, dim3(NCH, 32), tb, 0, stream, KT, VT, states);
    hipLaunchKernelGGL(scan_kernel, dim3(5, 32), tb, 0, stream, states);
    hipLaunchKernelGGL(attn_mfma, dim3(NCH, 32), tb, 0, stream, Qh, Kh, VT, states, atth);
    hipLaunchKernelGGL(gemm_out, dim3(64, 8), tb, 0, stream, atth, WtO, bo, out);
}